// Round 2
// baseline (86.437 us; speedup 1.0000x reference)
//
#include <hip/hip_runtime.h>

// scores[b,n] = 0.125 * X[b,n,:] . t[b,:]
//   t[b,d]    = sum_c Wq[c,d] * v[b,c]
//   v[b,c]    = Wk[c,:] . Xsum[b,:]
//   Xsum[b,:] = sum_n X[b,n,:]
// Wq = W_qkv rows [0,768), Wk = W_qkv rows [768,1536). scale = 64^-0.5 = 0.125.
//
// 4 graph nodes, no memset, no atomics:
//   K1 colsum_part : X -> part[b][64][768]      (plain float4 stores)
//   K2 v_kernel    : part -> xsum (LDS) -> v    (wave-per-c dot products)
//   K3 t_part      : W,v -> tpart[b][8][768]    (8-way c-split, plain stores)
//   K4 scores_k    : tpart-reduce in LDS, then wave-per-row X.t dots

#define DIM 768
#define BATCH 2
#define SEQ 2048

// ws layout (floats): part[2*64*768] @ 0, v[2*768] @ 98304, tpart[2*8*768] @ 99840

// K1: 128 blocks (2 batches x 64 chunks) x 192 threads; each block sums 32 rows.
__global__ void colsum_part(const float* __restrict__ X, float* __restrict__ part) {
    int b  = blockIdx.x >> 6;
    int ch = blockIdx.x & 63;
    int i  = threadIdx.x;                       // float4 index 0..191 (192*4 = 768)
    const float4* base = (const float4*)(X + ((size_t)b * SEQ + (size_t)ch * 32) * DIM) + i;
    float4 a = {0.f, 0.f, 0.f, 0.f};
    #pragma unroll 8
    for (int n = 0; n < 32; ++n) {
        float4 x = base[n * 192];
        a.x += x.x; a.y += x.y; a.z += x.z; a.w += x.w;
    }
    ((float4*)(part + (size_t)(b * 64 + ch) * DIM))[i] = a;
}

// K2: 96 blocks x 256 threads. Blocks 0..47 batch 0, 48..95 batch 1.
// Phase A: reduce 64 partials -> xs[768] in LDS. Phase B: each wave computes 4 v outputs.
__global__ void v_kernel(const float* __restrict__ W, const float* __restrict__ part,
                         float* __restrict__ v) {
    __shared__ alignas(16) float xs[DIM];
    int bi = blockIdx.x;
    int b = bi >= 48;
    int tid = threadIdx.x;
    for (int d = tid; d < DIM; d += 256) {
        float s = 0.f;
        #pragma unroll 8
        for (int ch = 0; ch < 64; ++ch)
            s += part[(size_t)(b * 64 + ch) * DIM + d];
        xs[d] = s;
    }
    __syncthreads();
    int gw = bi * 4 + (tid >> 6);
    int lane = tid & 63;
    const float4* xs4 = (const float4*)xs;
    #pragma unroll
    for (int k = 0; k < 4; ++k) {
        int o = gw * 4 + k;                     // 0..1535 = b*768 + c
        int c = o - b * DIM;
        const float4* wr = (const float4*)(W + (size_t)(DIM + c) * DIM);
        float acc = 0.f;
        #pragma unroll
        for (int j = 0; j < 3; ++j) {
            float4 a = wr[lane + 64 * j];
            float4 s = xs4[lane + 64 * j];
            acc += a.x * s.x + a.y * s.y + a.z * s.z + a.w * s.w;
        }
        #pragma unroll
        for (int off = 32; off; off >>= 1)
            acc += __shfl_down(acc, off, 64);
        if (lane == 0) v[o] = acc;
    }
}

// K3: 48 blocks (b x 8 csplit x 3 dchunk) x 256 threads; plain stores to tpart.
__global__ void t_part(const float* __restrict__ W, const float* __restrict__ v,
                       float* __restrict__ tp) {
    int bi = blockIdx.x;
    int b = bi / 24;
    int rem = bi % 24;
    int cs = rem / 3;
    int dch = rem % 3;
    int d = dch * 256 + threadIdx.x;
    const float* vb = v + b * DIM;
    float acc = 0.f;
    int c0 = cs * 96;
    #pragma unroll 8
    for (int c = c0; c < c0 + 96; ++c)
        acc += W[(size_t)c * DIM + d] * vb[c];  // coalesced across threads at fixed c
    tp[(size_t)(b * 8 + cs) * DIM + d] = acc;
}

// K4: 1024 blocks x 256 threads; 4 rows/block (all same batch: 512 blocks per batch).
// Stage t = sum of 8 tpart slices into LDS, then wave-per-row dot with X.
__global__ void scores_k(const float* __restrict__ X, const float* __restrict__ tp,
                         float* __restrict__ out) {
    __shared__ alignas(16) float ft[DIM];
    int r0 = blockIdx.x * 4;
    int b = r0 >> 11;
    int tid = threadIdx.x;
    if (tid < 192) {
        const float4* base = (const float4*)(tp + (size_t)b * 8 * DIM) + tid;
        float4 s = {0.f, 0.f, 0.f, 0.f};
        #pragma unroll
        for (int cs = 0; cs < 8; ++cs) {
            float4 a = base[cs * 192];
            s.x += a.x; s.y += a.y; s.z += a.z; s.w += a.w;
        }
        ((float4*)ft)[tid] = s;
    }
    __syncthreads();
    int r = r0 + (tid >> 6);
    int lane = tid & 63;
    const float4* xr = (const float4*)(X + (size_t)r * DIM);
    const float4* t4 = (const float4*)ft;
    float acc = 0.f;
    #pragma unroll
    for (int j = 0; j < 3; ++j) {
        float4 a = xr[lane + 64 * j];
        float4 s = t4[lane + 64 * j];
        acc += a.x * s.x + a.y * s.y + a.z * s.z + a.w * s.w;
    }
    #pragma unroll
    for (int off = 32; off; off >>= 1)
        acc += __shfl_down(acc, off, 64);
    if (lane == 0) out[r] = acc * 0.125f;
}

extern "C" void kernel_launch(void* const* d_in, const int* in_sizes, int n_in,
                              void* d_out, int out_size, void* d_ws, size_t ws_size,
                              hipStream_t stream) {
    const float* X = (const float*)d_in[0];   // [2, 2048, 768]
    const float* W = (const float*)d_in[1];   // [1536, 768]
    float* out = (float*)d_out;               // [2, 2048]
    float* ws = (float*)d_ws;
    float* part = ws;                         // [2, 64, 768]
    float* v    = ws + 2 * 64 * DIM;          // [2, 768]
    float* tp   = v + 2 * DIM;                // [2, 8, 768]

    colsum_part<<<128, 192, 0, stream>>>(X, part);
    v_kernel  <<<96, 256, 0, stream>>>(W, part, v);
    t_part    <<<48, 256, 0, stream>>>(W, v, tp);
    scores_k  <<<1024, 256, 0, stream>>>(X, tp, out);
}